// Round 4
// baseline (11725.248 us; speedup 1.0000x reference)
//
#include <hip/hip_runtime.h>

// GPT forward on MI355X. R3: input float dtype UNKNOWN (fp32 per reference,
// but harness may bf16-convert). A sniff kernel detects dtype from pos_emb
// bit patterns; all kernels branch wave-uniformly on the flag. Internal
// format fixed: fp32 residual h, bf16 MFMA operands. d_out dtype per flag.

typedef unsigned short ushort_t;
typedef unsigned int uint_t;
typedef __bf16 bf16x8 __attribute__((ext_vector_type(8)));
typedef float floatx4 __attribute__((ext_vector_type(4)));

#define D_ 768
#define T_ 2048
#define H_ 12
#define L_ 6
#define F_ 3072
#define V_ 32000

__device__ __forceinline__ float b2f(ushort_t u) {
    union { uint_t i; float f; } v; v.i = ((uint_t)u) << 16; return v.f;
}
__device__ __forceinline__ ushort_t f2b(float f) {
    uint_t x = __builtin_bit_cast(uint_t, f);
    uint_t r = (x + 0x7fffu + ((x >> 16) & 1u)) >> 16;
    return (ushort_t)r;
}
__device__ __forceinline__ float ldf(const void* p, size_t idx, int isbf) {
    return isbf ? b2f(((const ushort_t*)p)[idx]) : ((const float*)p)[idx];
}
__device__ __forceinline__ float wave_sum(float v) {
    for (int o = 32; o; o >>= 1) v += __shfl_xor(v, o);
    return v;
}
__device__ __forceinline__ float wave_max(float v) {
    for (int o = 32; o; o >>= 1) v = fmaxf(v, __shfl_xor(v, o));
    return v;
}

__global__ void sniff_kernel(const void* __restrict__ pos, int* __restrict__ flag) {
    if (threadIdx.x == 0 && blockIdx.x == 0) {
        const uint_t* w = (const uint_t*)pos;
        int c = 0;
        for (int i = 0; i < 64; ++i) {
            uint_t lo = w[i] & 0xffffu;
            int e = (int)((lo >> 7) & 0xff);
            if (e >= 110 && e < 127) ++c;
        }
        *flag = (c >= 32) ? 1 : 0;  // 1 = bf16 storage
    }
}

__global__ __launch_bounds__(256) void embed_kernel(
    const int* __restrict__ x, const void* __restrict__ tok,
    const void* __restrict__ pos, float* __restrict__ h,
    const int* __restrict__ flagp) {
    const int isbf = *flagp;
    int t = blockIdx.x, tid = threadIdx.x;
    int id = x[t];
    float* hr = h + (size_t)t * D_;
#pragma unroll
    for (int e = 0; e < 3; ++e) {
        int d = tid + e * 256;
        hr[d] = ldf(tok, (size_t)id * D_ + d, isbf) +
                ldf(pos, (size_t)t * D_ + d, isbf);
    }
}

__global__ __launch_bounds__(256) void ln_kernel(
    const float* __restrict__ x, const void* __restrict__ g, size_t go,
    const void* __restrict__ b, size_t bo, ushort_t* __restrict__ out,
    const int* __restrict__ flagp) {
    const int isbf = *flagp;
    int row = blockIdx.x, tid = threadIdx.x;
    int lane = tid & 63, wid = tid >> 6;
    const float* xr = x + (size_t)row * D_;
    float v0 = xr[tid], v1 = xr[tid + 256], v2 = xr[tid + 512];
    __shared__ float s1[4], s2[4];
    float s = wave_sum(v0 + v1 + v2);
    if (!lane) s1[wid] = s;
    __syncthreads();
    float mean = (s1[0] + s1[1] + s1[2] + s1[3]) * (1.f / 768.f);
    float d0 = v0 - mean, d1 = v1 - mean, d2 = v2 - mean;
    float q = wave_sum(d0 * d0 + d1 * d1 + d2 * d2);
    if (!lane) s2[wid] = q;
    __syncthreads();
    float var = (s2[0] + s2[1] + s2[2] + s2[3]) * (1.f / 768.f);
    float rstd = rsqrtf(var + 1e-5f);
    ushort_t* orow = out + (size_t)row * D_;
    orow[tid] = f2b(d0 * rstd * ldf(g, go + tid, isbf) + ldf(b, bo + tid, isbf));
    orow[tid + 256] = f2b(d1 * rstd * ldf(g, go + tid + 256, isbf) + ldf(b, bo + tid + 256, isbf));
    orow[tid + 512] = f2b(d2 * rstd * ldf(g, go + tid + 512, isbf) + ldf(b, bo + tid + 512, isbf));
}

// C[M,N] = A[M,K] * B[N,K]^T.  A: internal bf16. B/bias: flag dtype.
// EPI 0: bf16 store  1: +bias,GELU,bf16 store  2: resid+=  3: resid+=+bias
// EPI 4: store to d_out (dtype per flag)
template <int EPI>
__global__ __launch_bounds__(256) void gemm_bt(
    const ushort_t* __restrict__ A, const void* __restrict__ B, size_t Bo,
    const void* __restrict__ bias, size_t biaso, ushort_t* __restrict__ obf,
    float* __restrict__ resid, int M, int N, int K,
    const int* __restrict__ flagp) {
    const int isbf = *flagp;
    __shared__ ushort_t lds[8192];
    const int tid = threadIdx.x;
    const int lane = tid & 63;
    const int wid = tid >> 6;
    const int wm = wid >> 1, wn = wid & 1;
    const int m0 = blockIdx.y * 128, n0 = blockIdx.x * 128;
    const int lm = lane & 15, lq = lane >> 4;

    floatx4 acc[4][4] = {};

    const int arow = tid >> 2, aseg = tid & 3;
    const ushort_t* gA = A + (size_t)(m0 + arow) * K + aseg * 8;
    const size_t bofs = Bo + (size_t)(n0 + arow) * K + aseg * 8;
    const ushort_t* gBh = (const ushort_t*)B + bofs;
    const float* gBf = (const float*)B + bofs;
    ushort_t* sA = lds;
    ushort_t* sB = lds + 4096;

    for (int k0 = 0; k0 < K; k0 += 32) {
        *(uint4*)(sA + tid * 8) = *(const uint4*)(gA + k0);
        *(uint4*)(sA + 2048 + tid * 8) = *(const uint4*)(gA + (size_t)64 * K + k0);
        if (isbf) {
            *(uint4*)(sB + tid * 8) = *(const uint4*)(gBh + k0);
            *(uint4*)(sB + 2048 + tid * 8) = *(const uint4*)(gBh + (size_t)64 * K + k0);
        } else {
            union { ushort_t u[8]; uint4 v; } p0, p1;
            float4 x0 = *(const float4*)(gBf + k0);
            float4 x1 = *(const float4*)(gBf + k0 + 4);
            float4 y0 = *(const float4*)(gBf + (size_t)64 * K + k0);
            float4 y1 = *(const float4*)(gBf + (size_t)64 * K + k0 + 4);
            p0.u[0] = f2b(x0.x); p0.u[1] = f2b(x0.y); p0.u[2] = f2b(x0.z); p0.u[3] = f2b(x0.w);
            p0.u[4] = f2b(x1.x); p0.u[5] = f2b(x1.y); p0.u[6] = f2b(x1.z); p0.u[7] = f2b(x1.w);
            p1.u[0] = f2b(y0.x); p1.u[1] = f2b(y0.y); p1.u[2] = f2b(y0.z); p1.u[3] = f2b(y0.w);
            p1.u[4] = f2b(y1.x); p1.u[5] = f2b(y1.y); p1.u[6] = f2b(y1.z); p1.u[7] = f2b(y1.w);
            *(uint4*)(sB + tid * 8) = p0.v;
            *(uint4*)(sB + 2048 + tid * 8) = p1.v;
        }
        __syncthreads();
        bf16x8 af[4], bfr[4];
#pragma unroll
        for (int f = 0; f < 4; ++f) {
            af[f] = *(const bf16x8*)(sA + (wm * 64 + f * 16 + lm) * 32 + lq * 8);
            bfr[f] = *(const bf16x8*)(sB + (wn * 64 + f * 16 + lm) * 32 + lq * 8);
        }
#pragma unroll
        for (int i = 0; i < 4; ++i)
#pragma unroll
            for (int j = 0; j < 4; ++j)
                acc[i][j] = __builtin_amdgcn_mfma_f32_16x16x32_bf16(
                    af[i], bfr[j], acc[i][j], 0, 0, 0);
        __syncthreads();
    }

#pragma unroll
    for (int i = 0; i < 4; ++i) {
#pragma unroll
        for (int j = 0; j < 4; ++j) {
#pragma unroll
            for (int r = 0; r < 4; ++r) {
                int row = m0 + wm * 64 + i * 16 + lq * 4 + r;
                int col = n0 + wn * 64 + j * 16 + lm;
                float c = acc[i][j][r];
                if (EPI == 1 || EPI == 3) c += ldf(bias, biaso + col, isbf);
                if (EPI == 1) c = 0.5f * c * (1.f + erff(c * 0.70710678118f));
                size_t idx = (size_t)row * N + col;
                if (EPI == 0 || EPI == 1) {
                    obf[idx] = f2b(c);
                } else if (EPI == 4) {
                    if (isbf) obf[idx] = f2b(c);
                    else ((float*)obf)[idx] = c;
                } else {
                    resid[idx] += c;
                }
            }
        }
    }
}

__global__ __launch_bounds__(256) void attn_kernel(
    const ushort_t* __restrict__ qkv, ushort_t* __restrict__ ctx) {
    int gwave = blockIdx.x * 4 + (threadIdx.x >> 6);
    int lane = threadIdx.x & 63;
    int t = gwave / H_;
    int h = gwave - t * H_;

    const ushort_t* qrow = qkv + (size_t)t * (3 * D_) + h * 64;
    float q = b2f(qrow[lane]) * 0.125f;
    float m = -1e30f, l = 0.f, acc = 0.f;

    for (int j0 = 0; j0 <= t; j0 += 64) {
        int jm = t - j0;
        float s;
        {
            int j = j0 + lane;
            int jv = j <= t ? j : t;
            const uint4* k4 = (const uint4*)(qkv + (size_t)jv * (3 * D_) + D_ + h * 64);
            float sum = 0.f;
#pragma unroll
            for (int vv = 0; vv < 8; ++vv) {
                uint4 kv = k4[vv];
                uint_t w[4] = {kv.x, kv.y, kv.z, kv.w};
#pragma unroll
                for (int p = 0; p < 4; ++p) {
                    sum += __shfl(q, vv * 8 + p * 2) * b2f((ushort_t)(w[p] & 0xffff));
                    sum += __shfl(q, vv * 8 + p * 2 + 1) * b2f((ushort_t)(w[p] >> 16));
                }
            }
            s = (lane <= jm) ? sum : -1e30f;
        }
        float mn = fmaxf(m, wave_max(s));
        float p = (lane <= jm) ? __expf(s - mn) : 0.f;
        float alpha = __expf(m - mn);
        l = l * alpha + wave_sum(p);
        acc *= alpha;
        m = mn;
        const ushort_t* vbase = qkv + (size_t)j0 * (3 * D_) + 2 * D_ + h * 64 + lane;
        int iend = jm < 63 ? jm : 63;
        for (int i = 0; i <= iend; ++i) {
            acc += __shfl(p, i) * b2f(vbase[(size_t)i * (3 * D_)]);
        }
    }
    ctx[(size_t)t * D_ + h * 64 + lane] = f2b(acc / fmaxf(l, 1e-30f));
}

__global__ __launch_bounds__(256) void loss_rows(
    const void* __restrict__ logits, const int* __restrict__ tg,
    float* __restrict__ rowacc, const int* __restrict__ flagp) {
    const int isbf = *flagp;
    int t = blockIdx.x, tid = threadIdx.x;
    int lane = tid & 63, wid = tid >> 6;
    const ushort_t* lrh = (const ushort_t*)logits + (size_t)t * V_;
    const float* lrf = (const float*)logits + (size_t)t * V_;
    __shared__ float sm[4], ss[4];
    float mx = -1e30f;
    for (int j = tid; j < V_ / 8; j += 256) {
        float v[8];
        if (isbf) {
            uint4 u = ((const uint4*)lrh)[j];
            uint_t w[4] = {u.x, u.y, u.z, u.w};
#pragma unroll
            for (int p = 0; p < 4; ++p) {
                v[p * 2] = b2f((ushort_t)(w[p] & 0xffff));
                v[p * 2 + 1] = b2f((ushort_t)(w[p] >> 16));
            }
        } else {
            float4 a = ((const float4*)lrf)[j * 2];
            float4 bq = ((const float4*)lrf)[j * 2 + 1];
            v[0] = a.x; v[1] = a.y; v[2] = a.z; v[3] = a.w;
            v[4] = bq.x; v[5] = bq.y; v[6] = bq.z; v[7] = bq.w;
        }
#pragma unroll
        for (int p = 0; p < 8; ++p) mx = fmaxf(mx, v[p]);
    }
    mx = wave_max(mx);
    if (!lane) sm[wid] = mx;
    __syncthreads();
    mx = fmaxf(fmaxf(sm[0], sm[1]), fmaxf(sm[2], sm[3]));
    float se = 0.f;
    for (int j = tid; j < V_ / 8; j += 256) {
        float v[8];
        if (isbf) {
            uint4 u = ((const uint4*)lrh)[j];
            uint_t w[4] = {u.x, u.y, u.z, u.w};
#pragma unroll
            for (int p = 0; p < 4; ++p) {
                v[p * 2] = b2f((ushort_t)(w[p] & 0xffff));
                v[p * 2 + 1] = b2f((ushort_t)(w[p] >> 16));
            }
        } else {
            float4 a = ((const float4*)lrf)[j * 2];
            float4 bq = ((const float4*)lrf)[j * 2 + 1];
            v[0] = a.x; v[1] = a.y; v[2] = a.z; v[3] = a.w;
            v[4] = bq.x; v[5] = bq.y; v[6] = bq.z; v[7] = bq.w;
        }
#pragma unroll
        for (int p = 0; p < 8; ++p) se += __expf(v[p] - mx);
    }
    se = wave_sum(se);
    if (!lane) ss[wid] = se;
    __syncthreads();
    if (tid == 0) {
        se = ss[0] + ss[1] + ss[2] + ss[3];
        int tv = tg[t];
        float lv = isbf ? b2f(lrh[tv]) : lrf[tv];
        float nll = mx + __logf(se) - lv;
        rowacc[t] = (tv != 0) ? nll : 0.f;
        rowacc[T_ + t] = (tv != 0) ? 1.f : 0.f;
    }
}

__global__ __launch_bounds__(256) void loss_final(
    const float* __restrict__ rowacc, void* __restrict__ out,
    const int* __restrict__ flagp) {
    const int isbf = *flagp;
    int tid = threadIdx.x;
    int lane = tid & 63, wid = tid >> 6;
    float s = 0.f, c = 0.f;
    for (int i = tid; i < T_; i += 256) { s += rowacc[i]; c += rowacc[T_ + i]; }
    __shared__ float sa[4], sb[4];
    s = wave_sum(s); c = wave_sum(c);
    if (!lane) { sa[wid] = s; sb[wid] = c; }
    __syncthreads();
    if (tid == 0) {
        float S = sa[0] + sa[1] + sa[2] + sa[3];
        float C = sb[0] + sb[1] + sb[2] + sb[3];
        float loss = S / fmaxf(C, 1.f);
        size_t o = (size_t)T_ * V_;
        if (isbf) ((ushort_t*)out)[o] = f2b(loss);
        else ((float*)out)[o] = loss;
    }
}

extern "C" void kernel_launch(void* const* d_in, const int* in_sizes, int n_in,
                              void* d_out, int out_size, void* d_ws,
                              size_t ws_size, hipStream_t stream) {
    const int* x = (const int*)d_in[0];
    const int* targets = (const int*)d_in[1];
    const void* tok_emb = d_in[2];
    const void* pos_emb = d_in[3];
    const void* Wqkv = d_in[4];
    const void* Wo = d_in[5];
    const void* ln1_g = d_in[6];
    const void* ln1_b = d_in[7];
    const void* ln2_g = d_in[8];
    const void* ln2_b = d_in[9];
    const void* W1 = d_in[10];
    const void* b1 = d_in[11];
    const void* W2 = d_in[12];
    const void* b2 = d_in[13];
    const void* lnf_g = d_in[14];
    const void* lnf_b = d_in[15];

    char* ws = (char*)d_ws;
    float* h = (float*)ws;                    // 6.29 MB
    ushort_t* hn = (ushort_t*)(ws + 6291456); // 3.15 MB
    ushort_t* qkvb = (ushort_t*)(ws + 9437184);  // 9.44 MB
    ushort_t* ctxb = (ushort_t*)(ws + 18874368); // 3.15 MB
    ushort_t* ff1 = qkvb;                     // alias, disjoint lifetime
    float* rowacc = (float*)(ws + 22020096);  // 16 KB
    int* d_flag = (int*)(ws + 22036480);

    sniff_kernel<<<1, 64, 0, stream>>>(pos_emb, d_flag);
    embed_kernel<<<T_, 256, 0, stream>>>(x, tok_emb, pos_emb, h, d_flag);

    for (int l = 0; l < L_; ++l) {
        size_t oln = (size_t)l * D_;
        ln_kernel<<<T_, 256, 0, stream>>>(h, ln1_g, oln, ln1_b, oln, hn, d_flag);
        gemm_bt<0><<<dim3(3 * D_ / 128, T_ / 128), 256, 0, stream>>>(
            hn, Wqkv, (size_t)l * 3 * D_ * D_, nullptr, 0, qkvb, nullptr,
            T_, 3 * D_, D_, d_flag);
        attn_kernel<<<T_ * H_ / 4, 256, 0, stream>>>(qkvb, ctxb);
        gemm_bt<2><<<dim3(D_ / 128, T_ / 128), 256, 0, stream>>>(
            ctxb, Wo, (size_t)l * D_ * D_, nullptr, 0, nullptr, h,
            T_, D_, D_, d_flag);
        ln_kernel<<<T_, 256, 0, stream>>>(h, ln2_g, oln, ln2_b, oln, hn, d_flag);
        gemm_bt<1><<<dim3(F_ / 128, T_ / 128), 256, 0, stream>>>(
            hn, W1, (size_t)l * F_ * D_, b1, (size_t)l * F_, ff1, nullptr,
            T_, F_, D_, d_flag);
        gemm_bt<3><<<dim3(D_ / 128, T_ / 128), 256, 0, stream>>>(
            ff1, W2, (size_t)l * D_ * F_, b2, (size_t)l * D_, nullptr, h,
            T_, D_, F_, d_flag);
    }

    ln_kernel<<<T_, 256, 0, stream>>>(h, lnf_g, 0, lnf_b, 0, hn, d_flag);
    gemm_bt<4><<<dim3(V_ / 128, T_ / 128), 256, 0, stream>>>(
        hn, tok_emb, 0, nullptr, 0, (ushort_t*)d_out, nullptr,
        T_, V_, D_, d_flag);
    loss_rows<<<T_, 256, 0, stream>>>(d_out, targets, rowacc, d_flag);
    loss_final<<<1, 256, 0, stream>>>(rowacc, d_out, d_flag);
}